// Round 20
// baseline (60.516 us; speedup 1.0000x reference)
//
#include <hip/hip_runtime.h>

namespace {
constexpr int kNP = 8, kNR = 12;
constexpr int kRelCell = 288;          // NP*K*NR floats per cell (1152 B)
constexpr int kH = 64, kNOUT = 64;
constexpr int CELLS = 2;               // cells per wave
constexpr int WAVES = 8;               // 512-thread blocks
constexpr int WT_LD = 65;              // padded: conflict-free
}

__device__ __forceinline__ float readlane_f(float v, int l) {
    union { float f; int i; } u; u.f = v;
    u.i = __builtin_amdgcn_readlane(u.i, l);
    return u.f;
}

// DPP add step on the VALU pipe; invalid source lanes contribute 0.
template<int CTRL>
__device__ __forceinline__ float dpp_add(float x) {
    int y = __builtin_amdgcn_update_dpp(0, __float_as_int(x), CTRL, 0xf, 0xf, true);
    return x + __int_as_float(y);
}
// 64-lane sum (no DS ops); lane 63 holds the total.
__device__ __forceinline__ float wave_sum63(float x) {
    x = dpp_add<0x111>(x);  // row_shr:1
    x = dpp_add<0x112>(x);  // row_shr:2
    x = dpp_add<0x114>(x);  // row_shr:4
    x = dpp_add<0x118>(x);  // row_shr:8
    x = dpp_add<0x142>(x);  // row_bcast:15
    x = dpp_add<0x143>(x);  // row_bcast:31
    return x;
}

// Load one 288-float cell into the wave's registers, coalesced:
// pfa (float4 at lane*4) covers floats 0..255; pfb (224+lane) covers 224..287.
__device__ __forceinline__ void load_cell(const float* cb, int lane,
                                          float4* a, float* b) {
    *a = *(const float4*)(cb + lane * 4);
    *b = cb[224 + lane];
}

// Broadcast rel[idx] (idx compile-time constant after unroll) from the wave's
// own registers via v_readlane -- no memory access, no drains.
__device__ __forceinline__ float get_rel(const float4 pfa, const float pfb, int idx) {
    if (idx >= 256) return readlane_f(pfb, idx - 224);   // lanes 32..63
    const int c = idx & 3;
    const float v = (c == 0) ? pfa.x : (c == 1) ? pfa.y : (c == 2) ? pfa.z : pfa.w;
    return readlane_f(v, idx >> 2);
}

// One cell's logits+softmax+combine, consuming rel ENTIRELY from registers.
// wz2 pre-scaled by log2(e); raw v_exp_f32, no max subtraction (logits
// bounded far below exp2's 127), v_rcp vs precise divide (1 ulp, thr 0.2%).
__device__ __forceinline__ float cell_z(const float4 pfa, const float pfb,
                                        const float* __restrict__ dreg,
                                        float sv_i, float wz2) {
    float zj[kNP], la[kNP];
#pragma unroll
    for (int p = 0; p < kNP; ++p) {
        float d0 = 0.f, d1 = 0.f, d2 = 0.f;
#pragma unroll
        for (int r = 0; r < kNR; ++r) {
            d0 = fmaf(get_rel(pfa, pfb, p * 36 + r),      dreg[r], d0);
            d1 = fmaf(get_rel(pfa, pfb, p * 36 + 12 + r), dreg[r], d1);
            d2 = fmaf(get_rel(pfa, pfb, p * 36 + 24 + r), dreg[r], d2);
        }
        const float z = d0 * d1 * d2 * sv_i;
        zj[p] = z;
        la[p] = z * wz2;
    }
#pragma unroll
    for (int p = 0; p < kNP; ++p) la[p] = wave_sum63(la[p]);
    float esum = 0.f, zd = 0.f;
#pragma unroll
    for (int p = 0; p < kNP; ++p) {
        const float e = __builtin_amdgcn_exp2f(readlane_f(la[p], 63));
        esum += e;
        zd = fmaf(e, zj[p], zd);
    }
    return zd * __builtin_amdgcn_rcpf(esum);
}

// grid: 128 (b,v) x 16 f = 2048 blocks of 512 threads (8 waves); wave w ->
// t = 2w..2w+1 (round-15 champion geometry). ONLY change: rel is consumed
// from the wave's own registers via v_readlane broadcast (the 2 coalesced
// loads per cell already hold all 288 floats across the wave's lanes) --
// the compute phase has ZERO memory dependencies, eliminating the scalar-
// batch drain serialization that capped VALUBusy at ~50%.
__global__ __launch_bounds__(512, 4) void gal_kernel(
    const float* __restrict__ rel,      // (BS,NV,MF,MT,NP,K,NR)
    const float* __restrict__ se,       // (BS,NV,MT,MF,H)
    const float* __restrict__ s,        // unused (cancels in softmax)
    const float* __restrict__ Wstack,   // (NR,H,H)
    const float* __restrict__ lin_w,    // (1,H+NOUT)
    const float* __restrict__ lin_b,    // unused (cancels)
    const float* __restrict__ out_w,    // (NOUT,H)
    const float* __restrict__ out_b,    // (NOUT,)
    float* __restrict__ out)            // (BS,NV,NOUT)
{
    __shared__ __align__(16) float wT[kH * WT_LD];     // 16.25 KB
    __shared__ __align__(16) float dshare[kNR * kH];   // 3 KB diag; reused as redbuf

    const int tid  = (int)threadIdx.x;
    const int lane = tid & 63;
    const int w    = __builtin_amdgcn_readfirstlane(tid >> 6);  // uniform wave id 0..7

    const int bv = (int)blockIdx.x >> 4;   // 0..127
    const int f  = (int)blockIdx.x & 15;
    const int t0 = w * CELLS;

    const float* relbase = rel + ((size_t)((bv * 16 + f) * 16) + t0) * kRelCell;

    // load both cells into registers immediately (coalesced; drained at B1)
    float4 pfa0, pfa1; float pfb0, pfb1;
    load_cell(relbase,            lane, &pfa0, &pfb0);
    load_cell(relbase + kRelCell, lane, &pfa1, &pfb1);

    // out_w (o,d) -> wT[d*65+o]; stride-65 writes -> distinct banks
    for (int i = tid; i < kH * kNOUT; i += 512) {
        const int o = i >> 6, d = i & 63;
        wT[d * WT_LD + o] = out_w[i];
    }
    // diag gather (stride-65 in Wstack) once per block
    for (int i = tid; i < kNR * kH; i += 512) {
        const int r = i >> 6, d = i & 63;
        dshare[i] = Wstack[r * kH * kH + d * (kH + 1)];
    }

    const float wz2 = lin_w[kNOUT + lane] * 1.44269504088896340736f;  // log2(e)
    const float ob = out_b[lane];   // lane = o in epilogue
    const float* sep = se + ((size_t)(bv * 16 + t0) * 16 + f) * kH + lane;
    float sev[CELLS];
#pragma unroll
    for (int i = 0; i < CELLS; ++i) sev[i] = sep[(size_t)i * (16 * kH)];

    __syncthreads();                 // B1: wT + dshare staged, cell loads landed
    float dreg[kNR];
#pragma unroll
    for (int r = 0; r < kNR; ++r) dreg[r] = dshare[r * kH + lane];  // stride-1
    __syncthreads();                 // B2: diag consumed -> dshare free for redbuf

    float zreg[CELLS];
    zreg[0] = cell_z(pfa0, pfb0, dreg, sev[0], wz2);
    zreg[1] = cell_z(pfa1, pfb1, dreg, sev[1], wz2);

    // epilogue: batched 64x64 matvec over 2 cells; lane = o
    float q0 = 0.f, q1 = 0.f;
#pragma unroll
    for (int d = 0; d < kH; ++d) {
        const float wv = wT[d * WT_LD + lane];
        q0 = fmaf(readlane_f(zreg[0], d), wv, q0);
        q1 = fmaf(readlane_f(zreg[1], d), wv, q1);
    }
    const float tot = fmaxf(q0 + ob, 0.f) + fmaxf(q1 + ob, 0.f);

    // block reduce (dshare[0..511] reused) -> one wave-atomic per block
    dshare[w * 64 + lane] = tot;
    __syncthreads();                 // B3
    if (w == 0) {
        float r = 0.f;
#pragma unroll
        for (int j = 0; j < WAVES; ++j) r += dshare[j * 64 + lane];
        atomicAdd(&out[bv * kNOUT + lane], r);
    }
}

extern "C" void kernel_launch(void* const* d_in, const int* in_sizes, int n_in,
                              void* d_out, int out_size, void* d_ws, size_t ws_size,
                              hipStream_t stream) {
    const float* rel   = (const float*)d_in[0];
    const float* sem   = (const float*)d_in[1];
    const float* s     = (const float*)d_in[2];
    const float* Wst   = (const float*)d_in[3];
    const float* lin_w = (const float*)d_in[4];
    const float* lin_b = (const float*)d_in[5];
    const float* out_w = (const float*)d_in[6];
    const float* out_b = (const float*)d_in[7];
    float* out = (float*)d_out;

    hipMemsetAsync(out, 0, sizeof(float) * 8 * 16 * kNOUT, stream);
    dim3 grid(2048), block(512);
    hipLaunchKernelGGL(gal_kernel, grid, block, 0, stream,
                       rel, sem, s, Wst, lin_w, lin_b, out_w, out_b, out);
}

// Round 21
// 57.899 us; speedup vs baseline: 1.0452x; 1.0452x over previous
//
#include <hip/hip_runtime.h>

namespace {
constexpr int kNP = 8, kNR = 12;
constexpr int kRelCell = 288;          // NP*K*NR floats per cell (1152 B)
constexpr int kHalf = 144;             // floats 144..287 staged in LDS
constexpr int kH = 64, kNOUT = 64;
constexpr int CELLS = 2;               // cells per wave
constexpr int WAVES = 8;               // 512-thread blocks
constexpr int WT_LD = 65;              // padded: conflict-free
}

__device__ __forceinline__ float readlane_f(float v, int l) {
    union { float f; int i; } u; u.f = v;
    u.i = __builtin_amdgcn_readlane(u.i, l);
    return u.f;
}

// DPP add step on the VALU pipe; invalid source lanes contribute 0.
template<int CTRL>
__device__ __forceinline__ float dpp_add(float x) {
    int y = __builtin_amdgcn_update_dpp(0, __float_as_int(x), CTRL, 0xf, 0xf, true);
    return x + __int_as_float(y);
}
// 64-lane sum (no DS ops); lane 63 holds the total.
__device__ __forceinline__ float wave_sum63(float x) {
    x = dpp_add<0x111>(x);  // row_shr:1
    x = dpp_add<0x112>(x);  // row_shr:2
    x = dpp_add<0x114>(x);  // row_shr:4
    x = dpp_add<0x118>(x);  // row_shr:8
    x = dpp_add<0x142>(x);  // row_bcast:15
    x = dpp_add<0x143>(x);  // row_bcast:31
    return x;
}

// L2-warming prefetch of the scalar half (floats 0..143 + tail overlap):
// float4 at lane*4 covers floats 0..255 -- warms both halves' lines cheaply.
__device__ __forceinline__ void pf_issue(const float* cb, int lane, float4* a) {
    *a = *(const float4*)(cb + lane * 4);
}
#define PF_SINK(a) asm volatile("" :: "v"((a).x), "v"((a).y), "v"((a).z), "v"((a).w))

// async global->LDS, 16 B/lane; LDS dest = uniform base + lane*16 (exec-masked)
__device__ __forceinline__ void gll16(const float* g, float* l) {
    __builtin_amdgcn_global_load_lds(
        (const __attribute__((address_space(1))) void*)g,
        (__attribute__((address_space(3))) void*)l, 16, 0, 0);
}
// stage floats 144..287 (576 B) of one cell: lanes 0..35
__device__ __forceinline__ void stage_half(const float* g, float* lds, int lane) {
    if (lane < 36) gll16(g + kHalf + lane * 4, lds);
}

// 12-term dot of one row (3 float4s) with dreg
__device__ __forceinline__ float dot12(const float4 r0, const float4 r1,
                                       const float4 r2,
                                       const float* __restrict__ dreg) {
    return r0.x*dreg[0] + r0.y*dreg[1] + r0.z*dreg[2] + r0.w*dreg[3]
         + r1.x*dreg[4] + r1.y*dreg[5] + r1.z*dreg[6] + r1.w*dreg[7]
         + r2.x*dreg[8] + r2.y*dreg[9] + r2.z*dreg[10] + r2.w*dreg[11];
}

// One cell's logits+softmax+combine; p-rows 0..3 from the scalar path (cbS,
// wave-uniform global) and p-rows 4..7 from LDS broadcast (cbL), interleaved
// so SMEM drains hide under DS reads and vice versa. wz2 pre-scaled by
// log2(e); raw v_exp_f32, no max subtraction, v_rcp (1 ulp vs 0.2% thr).
__device__ __forceinline__ float cell_z(const float* __restrict__ cbS,
                                        const float* __restrict__ cbL,
                                        const float* __restrict__ dreg,
                                        float sv_i, float wz2) {
    float zj[kNP], la[kNP];
#pragma unroll
    for (int h = 0; h < 4; ++h) {
        {   // scalar-path row p = h
            const float4* r4 = (const float4*)(cbS + h * 36);
            const float d0 = dot12(r4[0], r4[1], r4[2], dreg);
            const float d1 = dot12(r4[3], r4[4], r4[5], dreg);
            const float d2 = dot12(r4[6], r4[7], r4[8], dreg);
            const float z = d0 * d1 * d2 * sv_i;
            zj[h] = z;
            la[h] = z * wz2;
        }
        {   // LDS-path row p = h + 4 (offset (h+4)*36 - 144 = h*36 in cbL)
            const float4* r4 = (const float4*)(cbL + h * 36);
            const float d0 = dot12(r4[0], r4[1], r4[2], dreg);
            const float d1 = dot12(r4[3], r4[4], r4[5], dreg);
            const float d2 = dot12(r4[6], r4[7], r4[8], dreg);
            const float z = d0 * d1 * d2 * sv_i;
            zj[h + 4] = z;
            la[h + 4] = z * wz2;
        }
    }
#pragma unroll
    for (int p = 0; p < kNP; ++p) la[p] = wave_sum63(la[p]);
    float esum = 0.f, zd = 0.f;
#pragma unroll
    for (int p = 0; p < kNP; ++p) {
        const float e = __builtin_amdgcn_exp2f(readlane_f(la[p], 63));
        esum += e;
        zd = fmaf(e, zj[p], zd);
    }
    return zd * __builtin_amdgcn_rcpf(esum);
}

// grid: 128 (b,v) x 16 f = 2048 blocks of 512 threads (8 waves); wave w ->
// t = 2w..2w+1 (round-15 champion geometry). ONLY change: each cell's rel is
// SPLIT across pipes -- p 0..3 scalar s_load (2 drain batches instead of 4),
// p 4..7 via async global_load_lds + broadcast ds_read_b128 -- interleaved
// per-p so the two pipes' latencies overlap. LDS 28.9 KB -> 4 blocks/CU.
__global__ __launch_bounds__(512, 4) void gal_kernel(
    const float* __restrict__ rel,      // (BS,NV,MF,MT,NP,K,NR)
    const float* __restrict__ se,       // (BS,NV,MT,MF,H)
    const float* __restrict__ s,        // unused (cancels in softmax)
    const float* __restrict__ Wstack,   // (NR,H,H)
    const float* __restrict__ lin_w,    // (1,H+NOUT)
    const float* __restrict__ lin_b,    // unused (cancels)
    const float* __restrict__ out_w,    // (NOUT,H)
    const float* __restrict__ out_b,    // (NOUT,)
    float* __restrict__ out)            // (BS,NV,NOUT)
{
    __shared__ __align__(16) float wT[kH * WT_LD];              // 16.25 KB
    __shared__ __align__(16) float relh[WAVES][CELLS][kHalf];   // 9 KB
    __shared__ __align__(16) float dshare[kNR * kH];            // 3 KB diag; reused as redbuf

    const int tid  = (int)threadIdx.x;
    const int lane = tid & 63;
    const int w    = __builtin_amdgcn_readfirstlane(tid >> 6);  // uniform wave id 0..7

    const int bv = (int)blockIdx.x >> 4;   // 0..127
    const int f  = (int)blockIdx.x & 15;
    const int t0 = w * CELLS;

    const float* relbase = rel + ((size_t)((bv * 16 + f) * 16) + t0) * kRelCell;

    // issue async LDS staging of both cells' upper halves FIRST
    stage_half(relbase,            &relh[w][0][0], lane);
    stage_half(relbase + kRelCell, &relh[w][1][0], lane);
    // L2-warm the scalar halves (drained at B1)
    float4 pfa0, pfa1;
    pf_issue(relbase,            lane, &pfa0);
    pf_issue(relbase + kRelCell, lane, &pfa1);

    // out_w (o,d) -> wT[d*65+o]; stride-65 writes -> distinct banks
    for (int i = tid; i < kH * kNOUT; i += 512) {
        const int o = i >> 6, d = i & 63;
        wT[d * WT_LD + o] = out_w[i];
    }
    // diag gather (stride-65 in Wstack) once per block
    for (int i = tid; i < kNR * kH; i += 512) {
        const int r = i >> 6, d = i & 63;
        dshare[i] = Wstack[r * kH * kH + d * (kH + 1)];
    }

    const float wz2 = lin_w[kNOUT + lane] * 1.44269504088896340736f;  // log2(e)
    const float ob = out_b[lane];   // lane = o in epilogue
    const float* sep = se + ((size_t)(bv * 16 + t0) * 16 + f) * kH + lane;
    float sev[CELLS];
#pragma unroll
    for (int i = 0; i < CELLS; ++i) sev[i] = sep[(size_t)i * (16 * kH)];

    __syncthreads();                 // B1: wT + dshare + relh staging all landed
    float dreg[kNR];
#pragma unroll
    for (int r = 0; r < kNR; ++r) dreg[r] = dshare[r * kH + lane];  // stride-1
    __syncthreads();                 // B2: diag consumed -> dshare free for redbuf

    float zreg[CELLS];
    zreg[0] = cell_z(relbase,            &relh[w][0][0], dreg, sev[0], wz2);
    PF_SINK(pfa0);
    zreg[1] = cell_z(relbase + kRelCell, &relh[w][1][0], dreg, sev[1], wz2);
    PF_SINK(pfa1);

    // epilogue: batched 64x64 matvec over 2 cells; lane = o
    float q0 = 0.f, q1 = 0.f;
#pragma unroll
    for (int d = 0; d < kH; ++d) {
        const float wv = wT[d * WT_LD + lane];
        q0 = fmaf(readlane_f(zreg[0], d), wv, q0);
        q1 = fmaf(readlane_f(zreg[1], d), wv, q1);
    }
    const float tot = fmaxf(q0 + ob, 0.f) + fmaxf(q1 + ob, 0.f);

    // block reduce (dshare[0..511] reused) -> one wave-atomic per block
    dshare[w * 64 + lane] = tot;
    __syncthreads();                 // B3
    if (w == 0) {
        float r = 0.f;
#pragma unroll
        for (int j = 0; j < WAVES; ++j) r += dshare[j * 64 + lane];
        atomicAdd(&out[bv * kNOUT + lane], r);
    }
}

extern "C" void kernel_launch(void* const* d_in, const int* in_sizes, int n_in,
                              void* d_out, int out_size, void* d_ws, size_t ws_size,
                              hipStream_t stream) {
    const float* rel   = (const float*)d_in[0];
    const float* sem   = (const float*)d_in[1];
    const float* s     = (const float*)d_in[2];
    const float* Wst   = (const float*)d_in[3];
    const float* lin_w = (const float*)d_in[4];
    const float* lin_b = (const float*)d_in[5];
    const float* out_w = (const float*)d_in[6];
    const float* out_b = (const float*)d_in[7];
    float* out = (float*)d_out;

    hipMemsetAsync(out, 0, sizeof(float) * 8 * 16 * kNOUT, stream);
    dim3 grid(2048), block(512);
    hipLaunchKernelGGL(gal_kernel, grid, block, 0, stream,
                       rel, sem, s, Wst, lin_w, lin_b, out_w, out_b, out);
}

// Round 22
// 43.023 us; speedup vs baseline: 1.4066x; 1.3458x over previous
//
#include <hip/hip_runtime.h>

namespace {
constexpr int kNP = 8, kNR = 12;
constexpr int kRelCell = 288;          // NP*K*NR floats per cell (1152 B)
constexpr int kH = 64, kNOUT = 64;
constexpr int CELLS = 2;               // cells per wave
constexpr int WAVES = 8;               // 512-thread blocks
constexpr int WT_LD = 65;              // padded: conflict-free
}

typedef float v2f __attribute__((ext_vector_type(2)));

__device__ __forceinline__ float readlane_f(float v, int l) {
    union { float f; int i; } u; u.f = v;
    u.i = __builtin_amdgcn_readlane(u.i, l);
    return u.f;
}

// DPP add step on the VALU pipe; invalid source lanes contribute 0.
template<int CTRL>
__device__ __forceinline__ float dpp_add(float x) {
    int y = __builtin_amdgcn_update_dpp(0, __float_as_int(x), CTRL, 0xf, 0xf, true);
    return x + __int_as_float(y);
}
// 64-lane sum (no DS ops); lane 63 holds the total.
__device__ __forceinline__ float wave_sum63(float x) {
    x = dpp_add<0x111>(x);  // row_shr:1
    x = dpp_add<0x112>(x);  // row_shr:2
    x = dpp_add<0x114>(x);  // row_shr:4
    x = dpp_add<0x118>(x);  // row_shr:8
    x = dpp_add<0x142>(x);  // row_bcast:15
    x = dpp_add<0x143>(x);  // row_bcast:31
    return x;
}

// L2-warming prefetch of one 288-float cell: float4 covers floats 0..255,
// dword covers 224..287 -- complete, no OOB past the cell.
__device__ __forceinline__ void pf_issue(const float* cb, int lane,
                                         float4* a, float* b) {
    *a = *(const float4*)(cb + lane * 4);
    *b = cb[224 + lane];
}
// keep prefetch registers alive (placed AFTER the compute: waitcnt satisfied)
#define PF_SINK(a, b) asm volatile("" :: "v"((a).x), "v"((a).y), "v"((a).z), "v"((a).w), "v"(b))

// One cell's logits+softmax+combine; cb is wave-uniform -> scalar s_load path
// (s_load_dwordx2 pairs). Dots computed as 6 packed v_pk_fma_f32 + 1 h-add
// per 12-dot (full-rate packed f32 on CDNA4) -- ~40% fewer dot instrs.
// wz2 pre-scaled by log2(e); raw v_exp_f32, no max subtraction (logits
// bounded far below exp2's 127), v_rcp vs precise divide (1 ulp, thr 0.2%).
__device__ __forceinline__ float cell_z(const float* __restrict__ cb,
                                        const v2f* __restrict__ dreg2,
                                        float sv_i, float wz2) {
    float zj[kNP], la[kNP];
#pragma unroll
    for (int p = 0; p < kNP; ++p) {
        const v2f* r2 = (const v2f*)(cb + p * 36);   // 18 wave-uniform float2
        v2f a0 = {0.f, 0.f}, a1 = {0.f, 0.f}, a2 = {0.f, 0.f};
#pragma unroll
        for (int rr = 0; rr < 6; ++rr) {
            a0 = __builtin_elementwise_fma(r2[rr],      dreg2[rr], a0);
            a1 = __builtin_elementwise_fma(r2[6 + rr],  dreg2[rr], a1);
            a2 = __builtin_elementwise_fma(r2[12 + rr], dreg2[rr], a2);
        }
        const float d0 = a0.x + a0.y;
        const float d1 = a1.x + a1.y;
        const float d2 = a2.x + a2.y;
        const float z = d0 * d1 * d2 * sv_i;
        zj[p] = z;
        la[p] = z * wz2;
    }
#pragma unroll
    for (int p = 0; p < kNP; ++p) la[p] = wave_sum63(la[p]);
    float esum = 0.f, zd = 0.f;
#pragma unroll
    for (int p = 0; p < kNP; ++p) {
        const float e = __builtin_amdgcn_exp2f(readlane_f(la[p], 63));
        esum += e;
        zd = fmaf(e, zj[p], zd);
    }
    return zd * __builtin_amdgcn_rcpf(esum);
}

// grid: 128 (b,v) x 16 f = 2048 blocks of 512 threads (8 waves); wave w ->
// t = 2w..2w+1 (round-15 champion geometry/path). ONLY change: packed-pair
// dot products (v_pk_fma_f32) -- dot phase 288 -> ~168 instrs per cell.
__global__ __launch_bounds__(512, 4) void gal_kernel(
    const float* __restrict__ rel,      // (BS,NV,MF,MT,NP,K,NR)
    const float* __restrict__ se,       // (BS,NV,MT,MF,H)
    const float* __restrict__ s,        // unused (cancels in softmax)
    const float* __restrict__ Wstack,   // (NR,H,H)
    const float* __restrict__ lin_w,    // (1,H+NOUT)
    const float* __restrict__ lin_b,    // unused (cancels)
    const float* __restrict__ out_w,    // (NOUT,H)
    const float* __restrict__ out_b,    // (NOUT,)
    float* __restrict__ out)            // (BS,NV,NOUT)
{
    __shared__ __align__(16) float wT[kH * WT_LD];     // 16.25 KB
    __shared__ __align__(16) float dshare[kNR * kH];   // 3 KB diag; reused as redbuf

    const int tid  = (int)threadIdx.x;
    const int lane = tid & 63;
    const int w    = __builtin_amdgcn_readfirstlane(tid >> 6);  // uniform wave id 0..7

    const int bv = (int)blockIdx.x >> 4;   // 0..127
    const int f  = (int)blockIdx.x & 15;
    const int t0 = w * CELLS;

    const float* relbase = rel + ((size_t)((bv * 16 + f) * 16) + t0) * kRelCell;

    // prefetch both cells immediately (warm L2 for the scalar loads)
    float4 pfa0, pfa1; float pfb0, pfb1;
    pf_issue(relbase,            lane, &pfa0, &pfb0);
    pf_issue(relbase + kRelCell, lane, &pfa1, &pfb1);

    // out_w (o,d) -> wT[d*65+o]; stride-65 writes -> distinct banks
    for (int i = tid; i < kH * kNOUT; i += 512) {
        const int o = i >> 6, d = i & 63;
        wT[d * WT_LD + o] = out_w[i];
    }
    // diag gather (stride-65 in Wstack) once per block
    for (int i = tid; i < kNR * kH; i += 512) {
        const int r = i >> 6, d = i & 63;
        dshare[i] = Wstack[r * kH * kH + d * (kH + 1)];
    }

    const float wz2 = lin_w[kNOUT + lane] * 1.44269504088896340736f;  // log2(e)
    const float ob = out_b[lane];   // lane = o in epilogue
    const float* sep = se + ((size_t)(bv * 16 + t0) * 16 + f) * kH + lane;
    float sev[CELLS];
#pragma unroll
    for (int i = 0; i < CELLS; ++i) sev[i] = sep[(size_t)i * (16 * kH)];

    __syncthreads();                 // B1: wT + dshare staged (+ prefetch drained)
    v2f dreg2[6];
#pragma unroll
    for (int rr = 0; rr < 6; ++rr) {
        dreg2[rr].x = dshare[(2 * rr) * kH + lane];      // stride-1: conflict-free
        dreg2[rr].y = dshare[(2 * rr + 1) * kH + lane];
    }
    __syncthreads();                 // B2: diag consumed -> dshare free for redbuf

    float zreg[CELLS];
    zreg[0] = cell_z(relbase,            dreg2, sev[0], wz2);
    PF_SINK(pfa0, pfb0);
    zreg[1] = cell_z(relbase + kRelCell, dreg2, sev[1], wz2);
    PF_SINK(pfa1, pfb1);

    // epilogue: batched 64x64 matvec over 2 cells; lane = o
    float q0 = 0.f, q1 = 0.f;
#pragma unroll
    for (int d = 0; d < kH; ++d) {
        const float wv = wT[d * WT_LD + lane];
        q0 = fmaf(readlane_f(zreg[0], d), wv, q0);
        q1 = fmaf(readlane_f(zreg[1], d), wv, q1);
    }
    const float tot = fmaxf(q0 + ob, 0.f) + fmaxf(q1 + ob, 0.f);

    // block reduce (dshare[0..511] reused) -> one wave-atomic per block
    dshare[w * 64 + lane] = tot;
    __syncthreads();                 // B3
    if (w == 0) {
        float r = 0.f;
#pragma unroll
        for (int j = 0; j < WAVES; ++j) r += dshare[j * 64 + lane];
        atomicAdd(&out[bv * kNOUT + lane], r);
    }
}

extern "C" void kernel_launch(void* const* d_in, const int* in_sizes, int n_in,
                              void* d_out, int out_size, void* d_ws, size_t ws_size,
                              hipStream_t stream) {
    const float* rel   = (const float*)d_in[0];
    const float* sem   = (const float*)d_in[1];
    const float* s     = (const float*)d_in[2];
    const float* Wst   = (const float*)d_in[3];
    const float* lin_w = (const float*)d_in[4];
    const float* lin_b = (const float*)d_in[5];
    const float* out_w = (const float*)d_in[6];
    const float* out_b = (const float*)d_in[7];
    float* out = (float*)d_out;

    hipMemsetAsync(out, 0, sizeof(float) * 8 * 16 * kNOUT, stream);
    dim3 grid(2048), block(512);
    hipLaunchKernelGGL(gal_kernel, grid, block, 0, stream,
                       rel, sem, s, Wst, lin_w, lin_b, out_w, out_b, out);
}